// Round 1
// baseline (1225.774 us; speedup 1.0000x reference)
//
#include <hip/hip_runtime.h>

// GCN layer: out = scatter_add(norm * (x@W)[src] -> dst) + b, with self-loops
// N=10000, D=512, E=160000 (but read sizes from in_sizes).

#define D_DIM 512

// ---- degree kernels ----
__global__ void deg_init_kernel(float* __restrict__ deg, int N) {
    int i = blockIdx.x * blockDim.x + threadIdx.x;
    if (i < N) deg[i] = 1.0f;  // self-loop contributes 1
}

__global__ void deg_count_kernel(const int* __restrict__ dst, float* __restrict__ deg, int E) {
    int e = blockIdx.x * blockDim.x + threadIdx.x;
    if (e < E) atomicAdd(&deg[dst[e]], 1.0f);
}

__global__ void dinv_kernel(const float* __restrict__ deg, float* __restrict__ dinv, int N) {
    int i = blockIdx.x * blockDim.x + threadIdx.x;
    if (i < N) dinv[i] = rsqrtf(deg[i]);  // deg >= 1 always
}

// ---- GEMM: H[M,512] = X[M,512] @ W[512,512], fp32, 64x64 tile, 4x4/thread ----
#define BM 64
#define BN 64
#define BK 16

__global__ __launch_bounds__(256) void gemm_xw_kernel(const float* __restrict__ X,
                                                      const float* __restrict__ W,
                                                      float* __restrict__ H, int M) {
    const int K = D_DIM, N = D_DIM;
    __shared__ float As[BK][BM];      // A tile, transposed (k-major)
    __shared__ float Bs[BK][BN];

    int tid = threadIdx.x;
    int tx = tid & 15;        // 0..15 col group
    int ty = tid >> 4;        // 0..15 row group
    int block_row = blockIdx.x * BM;
    int block_col = blockIdx.y * BN;

    float acc[4][4] = {{0.f}};

    // A-load mapping: thread loads one float4: row = tid/4 (0..63), k4 = (tid%4)*4
    int a_row = tid >> 2;
    int a_k4  = (tid & 3) << 2;
    // B-load mapping: row k = tid/16 (0..15), col4 = (tid%16)*4
    int b_k  = tid >> 4;
    int b_c4 = (tid & 15) << 2;

    for (int k0 = 0; k0 < K; k0 += BK) {
        int gr = block_row + a_row;
        float4 av = make_float4(0.f, 0.f, 0.f, 0.f);
        if (gr < M) av = *(const float4*)(X + (size_t)gr * K + k0 + a_k4);
        As[a_k4 + 0][a_row] = av.x;
        As[a_k4 + 1][a_row] = av.y;
        As[a_k4 + 2][a_row] = av.z;
        As[a_k4 + 3][a_row] = av.w;

        float4 bv = *(const float4*)(W + (size_t)(k0 + b_k) * N + block_col + b_c4);
        *(float4*)&Bs[b_k][b_c4] = bv;

        __syncthreads();
        #pragma unroll
        for (int k = 0; k < BK; ++k) {
            float4 a4 = *(const float4*)&As[k][ty << 2];
            float4 b4 = *(const float4*)&Bs[k][tx << 2];
            float a[4] = {a4.x, a4.y, a4.z, a4.w};
            float b[4] = {b4.x, b4.y, b4.z, b4.w};
            #pragma unroll
            for (int i = 0; i < 4; ++i)
                #pragma unroll
                for (int j = 0; j < 4; ++j)
                    acc[i][j] = fmaf(a[i], b[j], acc[i][j]);
        }
        __syncthreads();
    }

    #pragma unroll
    for (int i = 0; i < 4; ++i) {
        int gr = block_row + (ty << 2) + i;
        if (gr < M) {
            float4 v = make_float4(acc[i][0], acc[i][1], acc[i][2], acc[i][3]);
            *(float4*)(H + (size_t)gr * N + block_col + (tx << 2)) = v;
        }
    }
}

// ---- epilogue: out = b + h * dinv^2 (self-loop term), fully initializes out ----
__global__ __launch_bounds__(256) void self_bias_kernel(const float* __restrict__ h,
                                                        const float* __restrict__ dinv,
                                                        const float* __restrict__ b,
                                                        float* __restrict__ out, int N) {
    int idx = blockIdx.x * blockDim.x + threadIdx.x;  // float4 index
    int row = idx >> 7;            // 128 float4 per row
    if (row >= N) return;
    int c4 = (idx & 127) << 2;
    float di = dinv[row];
    float nrm = di * di;
    float4 hv = *(const float4*)(h + (size_t)row * D_DIM + c4);
    float4 bv = *(const float4*)(b + c4);
    float4 o;
    o.x = bv.x + hv.x * nrm;
    o.y = bv.y + hv.y * nrm;
    o.z = bv.z + hv.z * nrm;
    o.w = bv.w + hv.w * nrm;
    *(float4*)(out + (size_t)row * D_DIM + c4) = o;
}

// ---- edge scatter: one block (128 threads) per edge, 4 atomics/thread ----
__global__ __launch_bounds__(128) void scatter_kernel(const float* __restrict__ h,
                                                      const int* __restrict__ src,
                                                      const int* __restrict__ dst,
                                                      const float* __restrict__ dinv,
                                                      float* __restrict__ out, int E) {
    int e = blockIdx.x;
    if (e >= E) return;
    int s = src[e];
    int d = dst[e];
    float norm = dinv[s] * dinv[d];
    int c4 = threadIdx.x << 2;
    float4 hv = *(const float4*)(h + (size_t)s * D_DIM + c4);
    float* o = out + (size_t)d * D_DIM + c4;
    atomicAdd(o + 0, hv.x * norm);
    atomicAdd(o + 1, hv.y * norm);
    atomicAdd(o + 2, hv.z * norm);
    atomicAdd(o + 3, hv.w * norm);
}

extern "C" void kernel_launch(void* const* d_in, const int* in_sizes, int n_in,
                              void* d_out, int out_size, void* d_ws, size_t ws_size,
                              hipStream_t stream) {
    const float* x  = (const float*)d_in[0];
    const int*   ei = (const int*)d_in[1];
    const float* W  = (const float*)d_in[2];
    const float* b  = (const float*)d_in[3];
    float* out = (float*)d_out;

    int N = in_sizes[0] / D_DIM;
    int E = in_sizes[1] / 2;
    const int* src = ei;       // edge_index[0]
    const int* dst = ei + E;   // edge_index[1]

    // workspace layout
    char* ws = (char*)d_ws;
    float* h    = (float*)ws;                                  // N*D floats
    float* deg  = (float*)(ws + (size_t)N * D_DIM * 4);        // N floats
    float* dinv = deg + ((N + 63) & ~63);                      // N floats, aligned-ish

    // 1. degree (self-loop = 1)
    deg_init_kernel<<<(N + 255) / 256, 256, 0, stream>>>(deg, N);
    deg_count_kernel<<<(E + 255) / 256, 256, 0, stream>>>(dst, deg, E);
    dinv_kernel<<<(N + 255) / 256, 256, 0, stream>>>(deg, dinv, N);

    // 2. h = x @ W
    dim3 ggrid((N + BM - 1) / BM, D_DIM / BN);
    gemm_xw_kernel<<<ggrid, 256, 0, stream>>>(x, W, h, N);

    // 3. out = b + h*dinv^2  (initializes every out element)
    int total4 = N * (D_DIM / 4);
    self_bias_kernel<<<(total4 + 255) / 256, 256, 0, stream>>>(h, dinv, b, out, N);

    // 4. edge scatter-add
    scatter_kernel<<<E, 128, 0, stream>>>(h, src, dst, dinv, out, E);
}

// Round 2
// 238.555 us; speedup vs baseline: 5.1383x; 5.1383x over previous
//
#include <hip/hip_runtime.h>

// GCN layer: out[i] = b + sum_{j in in(i)} h[j]*dinv[j]*dinv[i] + h[i]*dinv[i]^2
// where h = x@W, dinv = rsqrt(deg_in+1). N=10000, D=512, E=160000.
// Strategy: CSR-by-dst build (cheap, int atomics) + register-accumulating
// gather (no float atomics), fp32 tiled GEMM for h.

#define D_DIM 512

// ---- degree count (int) ----
__global__ void deg_init_kernel(int* __restrict__ deg, int N) {
    int i = blockIdx.x * blockDim.x + threadIdx.x;
    if (i < N) deg[i] = 0;
}

__global__ void deg_count_kernel(const int* __restrict__ dst, int* __restrict__ deg, int E) {
    int e = blockIdx.x * blockDim.x + threadIdx.x;
    if (e < E) atomicAdd(&deg[dst[e]], 1);
}

// ---- single-block exclusive scan over N (<= a few 10k), also writes cursor & dinv ----
__global__ __launch_bounds__(1024) void scan_kernel(const int* __restrict__ deg,
                                                    int* __restrict__ offs,
                                                    int* __restrict__ cursor,
                                                    float* __restrict__ dinv, int N) {
    __shared__ int smem[1024];
    __shared__ int carry_s;
    int tid = threadIdx.x;
    if (tid == 0) carry_s = 0;
    __syncthreads();
    for (int base = 0; base < N; base += 1024) {
        int idx = base + tid;
        int v = (idx < N) ? deg[idx] : 0;
        smem[tid] = v;
        __syncthreads();
        #pragma unroll
        for (int off = 1; off < 1024; off <<= 1) {
            int t = (tid >= off) ? smem[tid - off] : 0;
            __syncthreads();
            smem[tid] += t;
            __syncthreads();
        }
        int carry = carry_s;
        if (idx < N) {
            int excl = carry + smem[tid] - v;
            offs[idx] = excl;
            cursor[idx] = excl;
            dinv[idx] = rsqrtf((float)v + 1.0f);  // +1 self loop
        }
        __syncthreads();
        if (tid == 0) carry_s = carry + smem[1023];
        __syncthreads();
    }
    if (tid == 0) offs[N] = carry_s;
}

// ---- CSR fill: csr_src[pos] = src for each edge, bucketed by dst ----
__global__ void csr_fill_kernel(const int* __restrict__ src, const int* __restrict__ dst,
                                int* __restrict__ cursor, int* __restrict__ csr_src, int E) {
    int e = blockIdx.x * blockDim.x + threadIdx.x;
    if (e < E) {
        int d = dst[e];
        int pos = atomicAdd(&cursor[d], 1);
        csr_src[pos] = src[e];
    }
}

// ---- GEMM: H[M,512] = X[M,512] @ W[512,512], fp32, 64x64 tile, 4x4/thread ----
#define BM 64
#define BN 64
#define BK 16

__global__ __launch_bounds__(256) void gemm_xw_kernel(const float* __restrict__ X,
                                                      const float* __restrict__ W,
                                                      float* __restrict__ H, int M) {
    const int K = D_DIM, N = D_DIM;
    __shared__ float As[BK][BM];
    __shared__ float Bs[BK][BN];

    int tid = threadIdx.x;
    int tx = tid & 15;
    int ty = tid >> 4;
    int block_row = blockIdx.x * BM;
    int block_col = blockIdx.y * BN;

    float acc[4][4] = {{0.f}};

    int a_row = tid >> 2;
    int a_k4  = (tid & 3) << 2;
    int b_k  = tid >> 4;
    int b_c4 = (tid & 15) << 2;

    for (int k0 = 0; k0 < K; k0 += BK) {
        int gr = block_row + a_row;
        float4 av = make_float4(0.f, 0.f, 0.f, 0.f);
        if (gr < M) av = *(const float4*)(X + (size_t)gr * K + k0 + a_k4);
        As[a_k4 + 0][a_row] = av.x;
        As[a_k4 + 1][a_row] = av.y;
        As[a_k4 + 2][a_row] = av.z;
        As[a_k4 + 3][a_row] = av.w;

        float4 bv = *(const float4*)(W + (size_t)(k0 + b_k) * N + block_col + b_c4);
        *(float4*)&Bs[b_k][b_c4] = bv;

        __syncthreads();
        #pragma unroll
        for (int k = 0; k < BK; ++k) {
            float4 a4 = *(const float4*)&As[k][ty << 2];
            float4 b4 = *(const float4*)&Bs[k][tx << 2];
            float a[4] = {a4.x, a4.y, a4.z, a4.w};
            float b[4] = {b4.x, b4.y, b4.z, b4.w};
            #pragma unroll
            for (int i = 0; i < 4; ++i)
                #pragma unroll
                for (int j = 0; j < 4; ++j)
                    acc[i][j] = fmaf(a[i], b[j], acc[i][j]);
        }
        __syncthreads();
    }

    #pragma unroll
    for (int i = 0; i < 4; ++i) {
        int gr = block_row + (ty << 2) + i;
        if (gr < M) {
            float4 v = make_float4(acc[i][0], acc[i][1], acc[i][2], acc[i][3]);
            *(float4*)(H + (size_t)gr * N + block_col + (tx << 2)) = v;
        }
    }
}

// ---- gather: one block per dst node; acc init = bias + self-loop; no atomics ----
__global__ __launch_bounds__(128) void gather_kernel(const float* __restrict__ h,
                                                     const int* __restrict__ csr_src,
                                                     const int* __restrict__ offs,
                                                     const float* __restrict__ dinv,
                                                     const float* __restrict__ b,
                                                     float* __restrict__ out, int N) {
    int node = blockIdx.x;
    if (node >= N) return;
    int c4 = threadIdx.x << 2;

    float di = dinv[node];
    float4 acc = *(const float4*)(b + c4);
    {
        float self = di * di;
        float4 hv = *(const float4*)(h + (size_t)node * D_DIM + c4);
        acc.x += hv.x * self;
        acc.y += hv.y * self;
        acc.z += hv.z * self;
        acc.w += hv.w * self;
    }

    int start = offs[node];
    int end   = offs[node + 1];
    for (int j = start; j < end; ++j) {
        int s = csr_src[j];              // same addr across wave -> broadcast
        float norm = dinv[s] * di;
        float4 v = *(const float4*)(h + (size_t)s * D_DIM + c4);
        acc.x += v.x * norm;
        acc.y += v.y * norm;
        acc.z += v.z * norm;
        acc.w += v.w * norm;
    }
    *(float4*)(out + (size_t)node * D_DIM + c4) = acc;
}

extern "C" void kernel_launch(void* const* d_in, const int* in_sizes, int n_in,
                              void* d_out, int out_size, void* d_ws, size_t ws_size,
                              hipStream_t stream) {
    const float* x  = (const float*)d_in[0];
    const int*   ei = (const int*)d_in[1];
    const float* W  = (const float*)d_in[2];
    const float* b  = (const float*)d_in[3];
    float* out = (float*)d_out;

    int N = in_sizes[0] / D_DIM;
    int E = in_sizes[1] / 2;
    const int* src = ei;       // edge_index[0]
    const int* dst = ei + E;   // edge_index[1]

    // workspace layout
    char* ws = (char*)d_ws;
    size_t hbytes = (size_t)N * D_DIM * sizeof(float);
    int Npad = (N + 256) & ~255;  // room for N+1, 1KB-aligned sections
    float* h      = (float*)ws;
    int*   deg    = (int*)(ws + hbytes);
    int*   offs   = deg + Npad;
    int*   cursor = offs + Npad;
    float* dinv   = (float*)(cursor + Npad);
    int*   csr    = (int*)(dinv + Npad);

    // 1. degree by dst
    deg_init_kernel<<<(N + 255) / 256, 256, 0, stream>>>(deg, N);
    deg_count_kernel<<<(E + 255) / 256, 256, 0, stream>>>(dst, deg, E);

    // 2. exclusive scan -> offs/cursor, dinv
    scan_kernel<<<1, 1024, 0, stream>>>(deg, offs, cursor, dinv, N);

    // 3. CSR fill
    csr_fill_kernel<<<(E + 255) / 256, 256, 0, stream>>>(src, dst, cursor, csr, E);

    // 4. h = x @ W
    dim3 ggrid((N + BM - 1) / BM, D_DIM / BN);
    gemm_xw_kernel<<<ggrid, 256, 0, stream>>>(x, W, h, N);

    // 5. gather (fused bias + self-loop), writes out exactly once
    gather_kernel<<<N, 128, 0, stream>>>(h, csr, offs, dinv, b, out, N);
}

// Round 3
// 188.152 us; speedup vs baseline: 6.5148x; 1.2679x over previous
//
#include <hip/hip_runtime.h>
#include <stdint.h>

// GCN layer: out[i] = b + sum_{j in in(i)} h[j]*dinv[j]*dinv[i] + h[i]*dinv[i]^2
// h = x@W via fp16 MFMA (fp32 accumulate), CSR-by-dst gather (no float atomics).
// N=10000, D=512, E=160000.

#define D_DIM 512

typedef _Float16 half8 __attribute__((ext_vector_type(8)));
typedef float floatx4 __attribute__((ext_vector_type(4)));

// ---- degree count (int) ----
__global__ void deg_init_kernel(int* __restrict__ deg, int N) {
    int i = blockIdx.x * blockDim.x + threadIdx.x;
    if (i < N) deg[i] = 0;
}

__global__ void deg_count_kernel(const int* __restrict__ dst, int* __restrict__ deg, int E) {
    int e = blockIdx.x * blockDim.x + threadIdx.x;
    if (e < E) atomicAdd(&deg[dst[e]], 1);
}

// ---- single-block exclusive scan over N, writes offs/cursor/dinv ----
__global__ __launch_bounds__(1024) void scan_kernel(const int* __restrict__ deg,
                                                    int* __restrict__ offs,
                                                    int* __restrict__ cursor,
                                                    float* __restrict__ dinv, int N) {
    __shared__ int smem[1024];
    __shared__ int carry_s;
    int tid = threadIdx.x;
    if (tid == 0) carry_s = 0;
    __syncthreads();
    for (int base = 0; base < N; base += 1024) {
        int idx = base + tid;
        int v = (idx < N) ? deg[idx] : 0;
        smem[tid] = v;
        __syncthreads();
        #pragma unroll
        for (int off = 1; off < 1024; off <<= 1) {
            int t = (tid >= off) ? smem[tid - off] : 0;
            __syncthreads();
            smem[tid] += t;
            __syncthreads();
        }
        int carry = carry_s;
        if (idx < N) {
            int excl = carry + smem[tid] - v;
            offs[idx] = excl;
            cursor[idx] = excl;
            dinv[idx] = rsqrtf((float)v + 1.0f);  // +1 self loop
        }
        __syncthreads();
        if (tid == 0) carry_s = carry + smem[1023];
        __syncthreads();
    }
    if (tid == 0) offs[N] = carry_s;
}

// ---- CSR fill ----
__global__ void csr_fill_kernel(const int* __restrict__ src, const int* __restrict__ dst,
                                int* __restrict__ cursor, int* __restrict__ csr_src, int E) {
    int e = blockIdx.x * blockDim.x + threadIdx.x;
    if (e < E) {
        int d = dst[e];
        int pos = atomicAdd(&cursor[d], 1);
        csr_src[pos] = src[e];
    }
}

// ---- fp32 -> fp16 conversion of x (row-major, same layout) ----
__global__ void convert_x_kernel(const float* __restrict__ x, _Float16* __restrict__ Ah, int total8) {
    int i = blockIdx.x * blockDim.x + threadIdx.x;
    if (i >= total8) return;
    const float4* p = (const float4*)x + (size_t)i * 2;
    float4 a = p[0], bq = p[1];
    half8 h;
    h[0] = (_Float16)a.x;  h[1] = (_Float16)a.y;  h[2] = (_Float16)a.z;  h[3] = (_Float16)a.w;
    h[4] = (_Float16)bq.x; h[5] = (_Float16)bq.y; h[6] = (_Float16)bq.z; h[7] = (_Float16)bq.w;
    *((half8*)Ah + i) = h;
}

// ---- W[k][n] -> Wt[n][k] fp16 (tiled transpose) ----
__global__ __launch_bounds__(256) void convert_wt_kernel(const float* __restrict__ W,
                                                         _Float16* __restrict__ Bt) {
    __shared__ float tile[32][33];
    int tx = threadIdx.x & 31, ty = threadIdx.x >> 5;  // ty 0..7
    int k0 = blockIdx.x * 32, n0 = blockIdx.y * 32;
    #pragma unroll
    for (int r = ty; r < 32; r += 8)
        tile[r][tx] = W[(size_t)(k0 + r) * D_DIM + n0 + tx];
    __syncthreads();
    #pragma unroll
    for (int r = ty; r < 32; r += 8)
        Bt[(size_t)(n0 + r) * D_DIM + k0 + tx] = (_Float16)tile[tx][r];
}

// ---- MFMA GEMM: H[M,512] = Ah[M,512] @ Bt[512,512]^T, fp16 in / fp32 out ----
// 128x128 tile, BK=32, 256 threads = 4 waves in 2x2, each wave 64x64 = 4x4 MFMAs.
#define GBM 128
#define GBN 128
#define GBK 32
#define LDK 40   // padded LDS k-stride (fp16): 80B rows, 16B-aligned, low-conflict

__global__ __launch_bounds__(256) void gemm_mfma_kernel(const _Float16* __restrict__ A,
                                                        const _Float16* __restrict__ Bt,
                                                        float* __restrict__ H, int M) {
    __shared__ _Float16 Asl[GBM * LDK];
    __shared__ _Float16 Bsl[GBN * LDK];
    int tid  = threadIdx.x;
    int lane = tid & 63;
    int wave = tid >> 6;
    int wr = wave >> 1, wc = wave & 1;

    int rowbase = blockIdx.x * GBM;
    int colbase = blockIdx.y * GBN;

    // staging mapping: thread -> (row = tid>>2 [+64], k-chunk = (tid&3)*8)
    int s_r = tid >> 2;
    int s_k = (tid & 3) << 3;

    // fragment mapping
    int fm = lane & 15;
    int fk = (lane >> 4) << 3;  // 0,8,16,24

    floatx4 acc[4][4];
    #pragma unroll
    for (int i = 0; i < 4; ++i)
        #pragma unroll
        for (int j = 0; j < 4; ++j)
            #pragma unroll
            for (int e = 0; e < 4; ++e)
                acc[i][j][e] = 0.f;

    for (int k0 = 0; k0 < D_DIM; k0 += GBK) {
        int ar0 = rowbase + s_r;      if (ar0 >= M) ar0 = M - 1;
        int ar1 = rowbase + s_r + 64; if (ar1 >= M) ar1 = M - 1;
        half8 av0 = *(const half8*)(A  + (size_t)ar0 * D_DIM + k0 + s_k);
        half8 av1 = *(const half8*)(A  + (size_t)ar1 * D_DIM + k0 + s_k);
        half8 bv0 = *(const half8*)(Bt + (size_t)(colbase + s_r) * D_DIM + k0 + s_k);
        half8 bv1 = *(const half8*)(Bt + (size_t)(colbase + s_r + 64) * D_DIM + k0 + s_k);
        __syncthreads();
        *(half8*)(&Asl[s_r * LDK + s_k])        = av0;
        *(half8*)(&Asl[(s_r + 64) * LDK + s_k]) = av1;
        *(half8*)(&Bsl[s_r * LDK + s_k])        = bv0;
        *(half8*)(&Bsl[(s_r + 64) * LDK + s_k]) = bv1;
        __syncthreads();

        half8 afrag[4], bfrag[4];
        #pragma unroll
        for (int t = 0; t < 4; ++t) {
            afrag[t] = *(const half8*)(&Asl[(wr * 64 + t * 16 + fm) * LDK + fk]);
            bfrag[t] = *(const half8*)(&Bsl[(wc * 64 + t * 16 + fm) * LDK + fk]);
        }
        #pragma unroll
        for (int i = 0; i < 4; ++i)
            #pragma unroll
            for (int j = 0; j < 4; ++j)
                acc[i][j] = __builtin_amdgcn_mfma_f32_16x16x32_f16(afrag[i], bfrag[j], acc[i][j], 0, 0, 0);
    }

    // store: D[m][n], m = (lane>>4)*4 + r, n = lane&15
    int mrow0 = (lane >> 4) << 2;
    #pragma unroll
    for (int i = 0; i < 4; ++i) {
        #pragma unroll
        for (int j = 0; j < 4; ++j) {
            int col = colbase + wc * 64 + j * 16 + fm;
            #pragma unroll
            for (int r = 0; r < 4; ++r) {
                int row = rowbase + wr * 64 + i * 16 + mrow0 + r;
                if (row < M) H[(size_t)row * D_DIM + col] = acc[i][j][r];
            }
        }
    }
}

// ---- gather: one block per dst node; acc init = bias + self-loop; no atomics ----
__global__ __launch_bounds__(128) void gather_kernel(const float* __restrict__ h,
                                                     const int* __restrict__ csr_src,
                                                     const int* __restrict__ offs,
                                                     const float* __restrict__ dinv,
                                                     const float* __restrict__ b,
                                                     float* __restrict__ out, int N) {
    int node = blockIdx.x;
    if (node >= N) return;
    int c4 = threadIdx.x << 2;

    float di = dinv[node];
    float4 acc = *(const float4*)(b + c4);
    {
        float self = di * di;
        float4 hv = *(const float4*)(h + (size_t)node * D_DIM + c4);
        acc.x += hv.x * self;
        acc.y += hv.y * self;
        acc.z += hv.z * self;
        acc.w += hv.w * self;
    }

    int start = offs[node];
    int end   = offs[node + 1];
    for (int j = start; j < end; ++j) {
        int s = csr_src[j];
        float norm = dinv[s] * di;
        float4 v = *(const float4*)(h + (size_t)s * D_DIM + c4);
        acc.x += v.x * norm;
        acc.y += v.y * norm;
        acc.z += v.z * norm;
        acc.w += v.w * norm;
    }
    *(float4*)(out + (size_t)node * D_DIM + c4) = acc;
}

extern "C" void kernel_launch(void* const* d_in, const int* in_sizes, int n_in,
                              void* d_out, int out_size, void* d_ws, size_t ws_size,
                              hipStream_t stream) {
    const float* x  = (const float*)d_in[0];
    const int*   ei = (const int*)d_in[1];
    const float* W  = (const float*)d_in[2];
    const float* b  = (const float*)d_in[3];
    float* out = (float*)d_out;

    int N = in_sizes[0] / D_DIM;
    int E = in_sizes[1] / 2;
    const int* src = ei;       // edge_index[0]
    const int* dst = ei + E;   // edge_index[1]

    // workspace layout (all 16B aligned)
    char* ws = (char*)d_ws;
    size_t hbytes  = (size_t)N * D_DIM * sizeof(float);
    size_t ahbytes = (size_t)N * D_DIM * sizeof(_Float16);
    size_t btbytes = (size_t)D_DIM * D_DIM * sizeof(_Float16);
    int Npad = (N + 256) & ~255;
    float*    h    = (float*)ws;
    _Float16* Ah   = (_Float16*)(ws + hbytes);
    _Float16* Bt   = (_Float16*)(ws + hbytes + ahbytes);
    int*      deg    = (int*)(ws + hbytes + ahbytes + btbytes);
    int*      offs   = deg + Npad;
    int*      cursor = offs + Npad;
    float*    dinv   = (float*)(cursor + Npad);
    int*      csr    = (int*)(dinv + Npad);

    // 1. degree by dst
    deg_init_kernel<<<(N + 255) / 256, 256, 0, stream>>>(deg, N);
    deg_count_kernel<<<(E + 255) / 256, 256, 0, stream>>>(dst, deg, E);

    // 2. exclusive scan -> offs/cursor, dinv
    scan_kernel<<<1, 1024, 0, stream>>>(deg, offs, cursor, dinv, N);

    // 3. CSR fill
    csr_fill_kernel<<<(E + 255) / 256, 256, 0, stream>>>(src, dst, cursor, csr, E);

    // 4. convert inputs to fp16 (and transpose W)
    int total8 = (N * D_DIM) / 8;
    convert_x_kernel<<<(total8 + 255) / 256, 256, 0, stream>>>(x, Ah, total8);
    convert_wt_kernel<<<dim3(D_DIM / 32, D_DIM / 32), 256, 0, stream>>>(W, Bt);

    // 5. h = x @ W via fp16 MFMA
    dim3 ggrid((N + GBM - 1) / GBM, D_DIM / GBN);
    gemm_mfma_kernel<<<ggrid, 256, 0, stream>>>(Ah, Bt, h, N);

    // 6. gather (fused bias + self-loop), writes out exactly once
    gather_kernel<<<N, 128, 0, stream>>>(h, csr, offs, dinv, b, out, N);
}

// Round 4
// 163.552 us; speedup vs baseline: 7.4947x; 1.1504x over previous
//
#include <hip/hip_runtime.h>
#include <stdint.h>

// GCN layer: out[i] = b + di * ( sum_{j in in(i)} pre[j] + pre[i] ),
// where pre[j] = dinv[j] * (x@W)[j] stored as fp16 (halves gather working set),
// dinv = rsqrt(deg_in+1), di = dinv[i]. GEMM via fp16 MFMA, fp32 accumulate.
// N=10000, D=512, E=160000.

#define D_DIM 512

typedef _Float16 half8 __attribute__((ext_vector_type(8)));
typedef float floatx4 __attribute__((ext_vector_type(4)));

// ---- degree count (int atomics; deg zeroed by hipMemsetAsync) ----
__global__ void deg_count_kernel(const int* __restrict__ dst, int* __restrict__ deg, int E) {
    int e = blockIdx.x * blockDim.x + threadIdx.x;
    if (e < E) atomicAdd(&deg[dst[e]], 1);
}

// ---- single-block exclusive scan (shuffle-based), writes offs/cursor/dinv ----
__global__ __launch_bounds__(1024) void scan_kernel(const int* __restrict__ deg,
                                                    int* __restrict__ offs,
                                                    int* __restrict__ cursor,
                                                    float* __restrict__ dinv, int N) {
    __shared__ int wsum[16];
    __shared__ int carry_s;
    int tid = threadIdx.x;
    int lane = tid & 63;
    int wid = tid >> 6;
    if (tid == 0) carry_s = 0;

    for (int base = 0; base < N; base += 1024) {
        int idx = base + tid;
        int v = (idx < N) ? deg[idx] : 0;
        int x = v;
        // wave-inclusive scan
        #pragma unroll
        for (int off = 1; off < 64; off <<= 1) {
            int t = __shfl_up(x, off, 64);
            if (lane >= off) x += t;
        }
        if (lane == 63) wsum[wid] = x;
        __syncthreads();                       // B1: wsum + carry_s visible
        int carry = carry_s;
        int wpre = 0;
        for (int w = 0; w < wid; ++w) wpre += wsum[w];
        if (idx < N) {
            int excl = carry + wpre + x - v;
            offs[idx] = excl;
            cursor[idx] = excl;
            dinv[idx] = rsqrtf((float)v + 1.0f);   // +1 self loop
        }
        __syncthreads();                       // B2: all reads of wsum/carry done
        if (tid == 0) {
            int tot = 0;
            for (int w = 0; w < 16; ++w) tot += wsum[w];
            carry_s = carry + tot;
        }
    }
    if (tid == 0) offs[N] = carry_s;
}

// ---- CSR fill ----
__global__ void csr_fill_kernel(const int* __restrict__ src, const int* __restrict__ dst,
                                int* __restrict__ cursor, int* __restrict__ csr_src, int E) {
    int e = blockIdx.x * blockDim.x + threadIdx.x;
    if (e < E) {
        int d = dst[e];
        int pos = atomicAdd(&cursor[d], 1);
        csr_src[pos] = src[e];
    }
}

// ---- merged convert: x -> fp16 A (row-major) and W -> fp16 Wt (transposed) ----
__global__ __launch_bounds__(256) void convert_kernel(const float* __restrict__ x,
                                                      const float* __restrict__ W,
                                                      _Float16* __restrict__ Ah,
                                                      _Float16* __restrict__ Bt,
                                                      int total8, int nxb) {
    __shared__ float tile[32][33];
    int bid = blockIdx.x;
    if (bid < nxb) {
        int i = bid * 256 + threadIdx.x;
        if (i < total8) {
            const float4* p = (const float4*)x + (size_t)i * 2;
            float4 a = p[0], bq = p[1];
            half8 h;
            h[0] = (_Float16)a.x;  h[1] = (_Float16)a.y;  h[2] = (_Float16)a.z;  h[3] = (_Float16)a.w;
            h[4] = (_Float16)bq.x; h[5] = (_Float16)bq.y; h[6] = (_Float16)bq.z; h[7] = (_Float16)bq.w;
            *((half8*)Ah + i) = h;
        }
        return;
    }
    int wt = bid - nxb;                    // 0..255
    int k0 = (wt & 15) * 32, n0 = (wt >> 4) * 32;
    int tx = threadIdx.x & 31, ty = threadIdx.x >> 5;
    #pragma unroll
    for (int r = ty; r < 32; r += 8)
        tile[r][tx] = W[(size_t)(k0 + r) * D_DIM + n0 + tx];
    __syncthreads();
    #pragma unroll
    for (int r = ty; r < 32; r += 8)
        Bt[(size_t)(n0 + r) * D_DIM + k0 + tx] = (_Float16)tile[tx][r];
}

// ---- MFMA GEMM: pre[M,512] = fp16( dinv[m] * (A @ Bt^T) ), fp16 in/out, fp32 acc ----
// 128x128 tile, BK=32, 256 threads = 4 waves 2x2, each wave 64x64 = 4x4 MFMAs.
#define GBM 128
#define GBN 128
#define GBK 32
#define LDK 40   // padded LDS k-stride (fp16): 80B rows, 16B-aligned, low-conflict

__global__ __launch_bounds__(256) void gemm_mfma_kernel(const _Float16* __restrict__ A,
                                                        const _Float16* __restrict__ Bt,
                                                        const float* __restrict__ dinv,
                                                        _Float16* __restrict__ pre, int M) {
    __shared__ _Float16 Asl[GBM * LDK];
    __shared__ _Float16 Bsl[GBN * LDK];
    int tid  = threadIdx.x;
    int lane = tid & 63;
    int wave = tid >> 6;
    int wr = wave >> 1, wc = wave & 1;

    int rowbase = blockIdx.x * GBM;
    int colbase = blockIdx.y * GBN;

    int s_r = tid >> 2;
    int s_k = (tid & 3) << 3;

    int fm = lane & 15;
    int fk = (lane >> 4) << 3;

    floatx4 acc[4][4];
    #pragma unroll
    for (int i = 0; i < 4; ++i)
        #pragma unroll
        for (int j = 0; j < 4; ++j)
            #pragma unroll
            for (int e = 0; e < 4; ++e)
                acc[i][j][e] = 0.f;

    for (int k0 = 0; k0 < D_DIM; k0 += GBK) {
        int ar0 = rowbase + s_r;      if (ar0 >= M) ar0 = M - 1;
        int ar1 = rowbase + s_r + 64; if (ar1 >= M) ar1 = M - 1;
        half8 av0 = *(const half8*)(A  + (size_t)ar0 * D_DIM + k0 + s_k);
        half8 av1 = *(const half8*)(A  + (size_t)ar1 * D_DIM + k0 + s_k);
        half8 bv0 = *(const half8*)(Bt + (size_t)(colbase + s_r) * D_DIM + k0 + s_k);
        half8 bv1 = *(const half8*)(Bt + (size_t)(colbase + s_r + 64) * D_DIM + k0 + s_k);
        __syncthreads();
        *(half8*)(&Asl[s_r * LDK + s_k])        = av0;
        *(half8*)(&Asl[(s_r + 64) * LDK + s_k]) = av1;
        *(half8*)(&Bsl[s_r * LDK + s_k])        = bv0;
        *(half8*)(&Bsl[(s_r + 64) * LDK + s_k]) = bv1;
        __syncthreads();

        half8 afrag[4], bfrag[4];
        #pragma unroll
        for (int t = 0; t < 4; ++t) {
            afrag[t] = *(const half8*)(&Asl[(wr * 64 + t * 16 + fm) * LDK + fk]);
            bfrag[t] = *(const half8*)(&Bsl[(wc * 64 + t * 16 + fm) * LDK + fk]);
        }
        #pragma unroll
        for (int i = 0; i < 4; ++i)
            #pragma unroll
            for (int j = 0; j < 4; ++j)
                acc[i][j] = __builtin_amdgcn_mfma_f32_16x16x32_f16(afrag[i], bfrag[j], acc[i][j], 0, 0, 0);
    }

    // store pre[m][n] = fp16(dinv[m] * acc); m = (lane>>4)*4 + r within 16-block
    int mrow0 = (lane >> 4) << 2;
    #pragma unroll
    for (int i = 0; i < 4; ++i) {
        #pragma unroll
        for (int j = 0; j < 4; ++j) {
            int col = colbase + wc * 64 + j * 16 + fm;
            #pragma unroll
            for (int r = 0; r < 4; ++r) {
                int row = rowbase + wr * 64 + i * 16 + mrow0 + r;
                if (row < M) {
                    float sc = dinv[row];
                    pre[(size_t)row * D_DIM + col] = (_Float16)(acc[i][j][r] * sc);
                }
            }
        }
    }
}

// ---- gather: one wave per dst node, 4 nodes/block; no atomics ----
__global__ __launch_bounds__(256) void gather_kernel(const _Float16* __restrict__ pre,
                                                     const int* __restrict__ csr_src,
                                                     const int* __restrict__ offs,
                                                     const float* __restrict__ dinv,
                                                     const float* __restrict__ b,
                                                     float* __restrict__ out, int N) {
    int wave = threadIdx.x >> 6;
    int lane = threadIdx.x & 63;
    int node = blockIdx.x * 4 + wave;
    if (node >= N) return;
    int c8 = lane << 3;

    float acc[8];
    {
        half8 self = *(const half8*)(pre + (size_t)node * D_DIM + c8);
        #pragma unroll
        for (int e = 0; e < 8; ++e) acc[e] = (float)self[e];
    }

    int start = offs[node];
    int end   = offs[node + 1];
    int j = start;
    for (; j + 1 < end; j += 2) {
        int s0 = csr_src[j];
        int s1 = csr_src[j + 1];
        half8 v0 = *(const half8*)(pre + (size_t)s0 * D_DIM + c8);
        half8 v1 = *(const half8*)(pre + (size_t)s1 * D_DIM + c8);
        #pragma unroll
        for (int e = 0; e < 8; ++e) acc[e] += (float)v0[e];
        #pragma unroll
        for (int e = 0; e < 8; ++e) acc[e] += (float)v1[e];
    }
    if (j < end) {
        int s0 = csr_src[j];
        half8 v0 = *(const half8*)(pre + (size_t)s0 * D_DIM + c8);
        #pragma unroll
        for (int e = 0; e < 8; ++e) acc[e] += (float)v0[e];
    }

    float di = dinv[node];
    float4 b0 = *(const float4*)(b + c8);
    float4 b1 = *(const float4*)(b + c8 + 4);
    float4 o0, o1;
    o0.x = b0.x + di * acc[0];
    o0.y = b0.y + di * acc[1];
    o0.z = b0.z + di * acc[2];
    o0.w = b0.w + di * acc[3];
    o1.x = b1.x + di * acc[4];
    o1.y = b1.y + di * acc[5];
    o1.z = b1.z + di * acc[6];
    o1.w = b1.w + di * acc[7];
    *(float4*)(out + (size_t)node * D_DIM + c8)     = o0;
    *(float4*)(out + (size_t)node * D_DIM + c8 + 4) = o1;
}

extern "C" void kernel_launch(void* const* d_in, const int* in_sizes, int n_in,
                              void* d_out, int out_size, void* d_ws, size_t ws_size,
                              hipStream_t stream) {
    const float* x  = (const float*)d_in[0];
    const int*   ei = (const int*)d_in[1];
    const float* W  = (const float*)d_in[2];
    const float* b  = (const float*)d_in[3];
    float* out = (float*)d_out;

    int N = in_sizes[0] / D_DIM;
    int E = in_sizes[1] / 2;
    const int* src = ei;       // edge_index[0]
    const int* dst = ei + E;   // edge_index[1]

    // workspace layout (16B aligned sections)
    char* ws = (char*)d_ws;
    size_t prebytes = (size_t)N * D_DIM * sizeof(_Float16);
    size_t ahbytes  = (size_t)N * D_DIM * sizeof(_Float16);
    size_t btbytes  = (size_t)D_DIM * D_DIM * sizeof(_Float16);
    int Npad = (N + 256) & ~255;
    _Float16* pre  = (_Float16*)ws;
    _Float16* Ah   = (_Float16*)(ws + prebytes);
    _Float16* Bt   = (_Float16*)(ws + prebytes + ahbytes);
    int*      deg    = (int*)(ws + prebytes + ahbytes + btbytes);
    int*      offs   = deg + Npad;
    int*      cursor = offs + Npad;
    float*    dinv   = (float*)(cursor + Npad);
    int*      csr    = (int*)(dinv + Npad);

    // 1. degree by dst
    hipMemsetAsync(deg, 0, (size_t)N * sizeof(int), stream);
    deg_count_kernel<<<(E + 255) / 256, 256, 0, stream>>>(dst, deg, E);

    // 2. exclusive scan -> offs/cursor, dinv
    scan_kernel<<<1, 1024, 0, stream>>>(deg, offs, cursor, dinv, N);

    // 3. CSR fill
    csr_fill_kernel<<<(E + 255) / 256, 256, 0, stream>>>(src, dst, cursor, csr, E);

    // 4. convert x -> fp16, W -> fp16 transposed (merged)
    int total8 = (N * D_DIM) / 8;
    int nxb = (total8 + 255) / 256;
    convert_kernel<<<nxb + 256, 256, 0, stream>>>(x, W, Ah, Bt, total8, nxb);

    // 5. pre = fp16(dinv * (x @ W)) via fp16 MFMA
    dim3 ggrid((N + GBM - 1) / GBM, D_DIM / GBN);
    gemm_mfma_kernel<<<ggrid, 256, 0, stream>>>(Ah, Bt, dinv, pre, N);

    // 6. gather: out = b + di*(sum pre[src] + pre[node])
    gather_kernel<<<(N + 3) / 4, 256, 0, stream>>>(pre, csr, offs, dinv, b, out, N);
}

// Round 6
// 155.747 us; speedup vs baseline: 7.8703x; 1.0501x over previous
//
#include <hip/hip_runtime.h>
#include <stdint.h>

// GCN layer: out[i] = b + di * ( sum_{j in in(i)} pre[j] + pre[i] ),
// pre[j] = dinv[j] * (x@W)[j] in fp16 (halves gather working set),
// dinv = rsqrt(deg_in+1). GEMM via fp16 MFMA, fp32 accumulate.
// N=10000, D=512, E=160000. 5 dispatches: memset, fused(deg+convert),
// scan, fused(csr_fill+gemm), gather.

#define D_DIM 512

typedef _Float16 half8 __attribute__((ext_vector_type(8)));
typedef float floatx4 __attribute__((ext_vector_type(4)));

// ---- K1: fused deg_count + convert_x + convert_Wt (all input-only deps) ----
__global__ __launch_bounds__(256) void fused_pre_kernel(const float* __restrict__ x,
                                                        const float* __restrict__ W,
                                                        const int* __restrict__ dst,
                                                        _Float16* __restrict__ Ah,
                                                        _Float16* __restrict__ Bt,
                                                        int* __restrict__ deg,
                                                        int total8, int nxb, int E) {
    __shared__ float tile[32][33];
    int bid = blockIdx.x;
    if (bid < nxb) {                       // convert x -> fp16 (row-major)
        int i = bid * 256 + threadIdx.x;
        if (i < total8) {
            const float4* p = (const float4*)x + (size_t)i * 2;
            float4 a = p[0], bq = p[1];
            half8 h;
            h[0] = (_Float16)a.x;  h[1] = (_Float16)a.y;  h[2] = (_Float16)a.z;  h[3] = (_Float16)a.w;
            h[4] = (_Float16)bq.x; h[5] = (_Float16)bq.y; h[6] = (_Float16)bq.z; h[7] = (_Float16)bq.w;
            *((half8*)Ah + i) = h;
        }
        return;
    }
    if (bid < nxb + 256) {                 // W[k][n] -> Bt[n][k] fp16
        int wt = bid - nxb;
        int k0 = (wt & 15) * 32, n0 = (wt >> 4) * 32;
        int tx = threadIdx.x & 31, ty = threadIdx.x >> 5;
        #pragma unroll
        for (int r = ty; r < 32; r += 8)
            tile[r][tx] = W[(size_t)(k0 + r) * D_DIM + n0 + tx];
        __syncthreads();
        #pragma unroll
        for (int r = ty; r < 32; r += 8)
            Bt[(size_t)(n0 + r) * D_DIM + k0 + tx] = (_Float16)tile[tx][r];
        return;
    }
    // degree count
    int e = (bid - nxb - 256) * 256 + threadIdx.x;
    if (e < E) atomicAdd(&deg[dst[e]], 1);
}

// ---- one-pass single-block scan: 1024 threads x C contiguous elements each ----
__global__ __launch_bounds__(1024) void scan_kernel(const int* __restrict__ deg,
                                                    int* __restrict__ offs,
                                                    int* __restrict__ cursor,
                                                    float* __restrict__ dinv, int N) {
    __shared__ int wsum[16];
    int tid = threadIdx.x;
    int lane = tid & 63;
    int wid = tid >> 6;
    const int C = (N + 1023) >> 10;        // elements per thread (10 for N=10000)
    int base = tid * C;

    int local[16];
    int sum = 0;
    for (int c = 0; c < C; ++c) {
        int idx = base + c;
        int v = (idx < N) ? deg[idx] : 0;
        local[c] = v;
        sum += v;
    }
    // block-wide exclusive scan of per-thread sums
    int xv = sum;
    #pragma unroll
    for (int off = 1; off < 64; off <<= 1) {
        int t = __shfl_up(xv, off, 64);
        if (lane >= off) xv += t;
    }
    if (lane == 63) wsum[wid] = xv;
    __syncthreads();
    int wpre = 0;
    for (int w = 0; w < wid; ++w) wpre += wsum[w];
    int run = wpre + xv - sum;             // exclusive prefix for this thread
    for (int c = 0; c < C; ++c) {
        int idx = base + c;
        if (idx < N) {
            offs[idx] = run;
            cursor[idx] = run;
            dinv[idx] = rsqrtf((float)local[c] + 1.0f);  // +1 self loop
            run += local[c];
        }
    }
    if (tid == 1023) offs[N] = run;        // = E
}

// ---- K2: fused csr_fill + MFMA GEMM ----
#define GBM 128
#define GBN 128
#define GBK 32
#define LDK 40   // padded LDS k-stride (fp16): 80B rows, 16B-aligned, low-conflict

__global__ __launch_bounds__(256) void fused_main_kernel(const _Float16* __restrict__ A,
                                                         const _Float16* __restrict__ Bt,
                                                         const float* __restrict__ dinv,
                                                         _Float16* __restrict__ pre,
                                                         const int* __restrict__ src,
                                                         const int* __restrict__ dst,
                                                         int* __restrict__ cursor,
                                                         int* __restrict__ csr_src,
                                                         int M, int E, int ngb, int gemm_blocks) {
    __shared__ _Float16 Asl[GBM * LDK];
    __shared__ _Float16 Bsl[GBN * LDK];

    if (blockIdx.x >= (unsigned)gemm_blocks) {   // ---- csr_fill part ----
        int e = (blockIdx.x - gemm_blocks) * 256 + threadIdx.x;
        if (e < E) {
            int d = dst[e];
            int pos = atomicAdd(&cursor[d], 1);
            csr_src[pos] = src[e];
        }
        return;
    }

    // ---- GEMM part: pre = fp16(dinv * (A @ Bt^T)) ----
    int tid  = threadIdx.x;
    int lane = tid & 63;
    int wave = tid >> 6;
    int wr = wave >> 1, wc = wave & 1;

    int rowbase = (blockIdx.x % ngb) * GBM;
    int colbase = (blockIdx.x / ngb) * GBN;

    int s_r = tid >> 2;
    int s_k = (tid & 3) << 3;

    int fm = lane & 15;
    int fk = (lane >> 4) << 3;

    floatx4 acc[4][4];
    #pragma unroll
    for (int i = 0; i < 4; ++i)
        #pragma unroll
        for (int j = 0; j < 4; ++j)
            #pragma unroll
            for (int e = 0; e < 4; ++e)
                acc[i][j][e] = 0.f;

    for (int k0 = 0; k0 < D_DIM; k0 += GBK) {
        int ar0 = rowbase + s_r;      if (ar0 >= M) ar0 = M - 1;
        int ar1 = rowbase + s_r + 64; if (ar1 >= M) ar1 = M - 1;
        half8 av0 = *(const half8*)(A  + (size_t)ar0 * D_DIM + k0 + s_k);
        half8 av1 = *(const half8*)(A  + (size_t)ar1 * D_DIM + k0 + s_k);
        half8 bv0 = *(const half8*)(Bt + (size_t)(colbase + s_r) * D_DIM + k0 + s_k);
        half8 bv1 = *(const half8*)(Bt + (size_t)(colbase + s_r + 64) * D_DIM + k0 + s_k);
        __syncthreads();
        *(half8*)(&Asl[s_r * LDK + s_k])        = av0;
        *(half8*)(&Asl[(s_r + 64) * LDK + s_k]) = av1;
        *(half8*)(&Bsl[s_r * LDK + s_k])        = bv0;
        *(half8*)(&Bsl[(s_r + 64) * LDK + s_k]) = bv1;
        __syncthreads();

        half8 afrag[4], bfrag[4];
        #pragma unroll
        for (int t = 0; t < 4; ++t) {
            afrag[t] = *(const half8*)(&Asl[(wr * 64 + t * 16 + fm) * LDK + fk]);
            bfrag[t] = *(const half8*)(&Bsl[(wc * 64 + t * 16 + fm) * LDK + fk]);
        }
        #pragma unroll
        for (int i = 0; i < 4; ++i)
            #pragma unroll
            for (int j = 0; j < 4; ++j)
                acc[i][j] = __builtin_amdgcn_mfma_f32_16x16x32_f16(afrag[i], bfrag[j], acc[i][j], 0, 0, 0);
    }

    int mrow0 = (lane >> 4) << 2;
    #pragma unroll
    for (int i = 0; i < 4; ++i) {
        #pragma unroll
        for (int j = 0; j < 4; ++j) {
            int col = colbase + wc * 64 + j * 16 + fm;
            #pragma unroll
            for (int r = 0; r < 4; ++r) {
                int row = rowbase + wr * 64 + i * 16 + mrow0 + r;
                if (row < M) {
                    float sc = dinv[row];
                    pre[(size_t)row * D_DIM + col] = (_Float16)(acc[i][j][r] * sc);
                }
            }
        }
    }
}

// ---- gather: one wave per dst node, 4 nodes/block, unroll-4 MLP ----
__global__ __launch_bounds__(256) void gather_kernel(const _Float16* __restrict__ pre,
                                                     const int* __restrict__ csr_src,
                                                     const int* __restrict__ offs,
                                                     const float* __restrict__ dinv,
                                                     const float* __restrict__ b,
                                                     float* __restrict__ out, int N) {
    int wave = threadIdx.x >> 6;
    int lane = threadIdx.x & 63;
    int node = blockIdx.x * 4 + wave;
    if (node >= N) return;
    int c8 = lane << 3;

    float acc[8];
    {
        half8 self = *(const half8*)(pre + (size_t)node * D_DIM + c8);
        #pragma unroll
        for (int e = 0; e < 8; ++e) acc[e] = (float)self[e];
    }

    int start = offs[node];
    int end   = offs[node + 1];
    int j = start;
    for (; j + 3 < end; j += 4) {
        int s0 = csr_src[j];
        int s1 = csr_src[j + 1];
        int s2 = csr_src[j + 2];
        int s3 = csr_src[j + 3];
        half8 v0 = *(const half8*)(pre + (size_t)s0 * D_DIM + c8);
        half8 v1 = *(const half8*)(pre + (size_t)s1 * D_DIM + c8);
        half8 v2 = *(const half8*)(pre + (size_t)s2 * D_DIM + c8);
        half8 v3 = *(const half8*)(pre + (size_t)s3 * D_DIM + c8);
        #pragma unroll
        for (int e = 0; e < 8; ++e)
            acc[e] += (float)v0[e] + (float)v1[e] + (float)v2[e] + (float)v3[e];
    }
    for (; j < end; ++j) {
        int s0 = csr_src[j];
        half8 v0 = *(const half8*)(pre + (size_t)s0 * D_DIM + c8);
        #pragma unroll
        for (int e = 0; e < 8; ++e) acc[e] += (float)v0[e];
    }

    float di = dinv[node];
    float4 b0 = *(const float4*)(b + c8);
    float4 b1 = *(const float4*)(b + c8 + 4);
    floatx4 o0, o1;
    o0[0] = b0.x + di * acc[0];
    o0[1] = b0.y + di * acc[1];
    o0[2] = b0.z + di * acc[2];
    o0[3] = b0.w + di * acc[3];
    o1[0] = b1.x + di * acc[4];
    o1[1] = b1.y + di * acc[5];
    o1[2] = b1.z + di * acc[6];
    o1[3] = b1.w + di * acc[7];
    // nontemporal: don't evict pre from L2 with the out stream
    __builtin_nontemporal_store(o0, (floatx4*)(out + (size_t)node * D_DIM + c8));
    __builtin_nontemporal_store(o1, (floatx4*)(out + (size_t)node * D_DIM + c8 + 4));
}

extern "C" void kernel_launch(void* const* d_in, const int* in_sizes, int n_in,
                              void* d_out, int out_size, void* d_ws, size_t ws_size,
                              hipStream_t stream) {
    const float* x  = (const float*)d_in[0];
    const int*   ei = (const int*)d_in[1];
    const float* W  = (const float*)d_in[2];
    const float* b  = (const float*)d_in[3];
    float* out = (float*)d_out;

    int N = in_sizes[0] / D_DIM;
    int E = in_sizes[1] / 2;
    const int* src = ei;       // edge_index[0]
    const int* dst = ei + E;   // edge_index[1]

    // workspace layout (16B aligned sections)
    char* ws = (char*)d_ws;
    size_t prebytes = (size_t)N * D_DIM * sizeof(_Float16);
    size_t ahbytes  = (size_t)N * D_DIM * sizeof(_Float16);
    size_t btbytes  = (size_t)D_DIM * D_DIM * sizeof(_Float16);
    int Npad = (N + 256) & ~255;
    _Float16* pre  = (_Float16*)ws;
    _Float16* Ah   = (_Float16*)(ws + prebytes);
    _Float16* Bt   = (_Float16*)(ws + prebytes + ahbytes);
    int*      deg    = (int*)(ws + prebytes + ahbytes + btbytes);
    int*      offs   = deg + Npad;
    int*      cursor = offs + Npad;
    float*    dinv   = (float*)(cursor + Npad);
    int*      csr    = (int*)(dinv + Npad);

    // 1. zero degree
    (void)hipMemsetAsync(deg, 0, (size_t)N * sizeof(int), stream);

    // 2. fused: convert x, convert+transpose W, degree count
    int total8 = (N * D_DIM) / 8;
    int nxb = (total8 + 255) / 256;
    int degb = (E + 255) / 256;
    fused_pre_kernel<<<nxb + 256 + degb, 256, 0, stream>>>(x, W, dst, Ah, Bt, deg, total8, nxb, E);

    // 3. one-pass scan -> offs/cursor, dinv
    scan_kernel<<<1, 1024, 0, stream>>>(deg, offs, cursor, dinv, N);

    // 4. fused: MFMA GEMM (pre = fp16(dinv * x@W)) + csr_fill
    int ngb = (N + GBM - 1) / GBM;
    int gemm_blocks = ngb * (D_DIM / GBN);
    fused_main_kernel<<<gemm_blocks + degb, 256, 0, stream>>>(Ah, Bt, dinv, pre, src, dst,
                                                              cursor, csr, N, E, ngb, gemm_blocks);

    // 5. gather: out = b + di*(sum pre[src] + pre[node])
    gather_kernel<<<(N + 3) / 4, 256, 0, stream>>>(pre, csr, offs, dinv, b, out, N);
}